// Round 21
// baseline (143.805 us; speedup 1.0000x reference)
//
#include <hip/hip_runtime.h>
#include <hip/hip_bf16.h>
#include <stdint.h>

#define N_NODES 50000
#define N_EDGES 800000
#define IN_C 512
#define HID_C 256
#define CAP 96          // max in-degree capacity (Poisson mean 16, ~12 sigma)

typedef __attribute__((ext_vector_type(8))) short bf16x8;
typedef __attribute__((ext_vector_type(4))) float f32x4;
typedef __attribute__((address_space(3))) uint32_t lds_u32_t;
typedef __attribute__((address_space(1))) const uint32_t g_u32_t;

__device__ __forceinline__ void g2l16(const void* g, void* l) {
    __builtin_amdgcn_global_load_lds((g_u32_t*)g, (lds_u32_t*)l, 16, 0, 0);
}

__device__ __forceinline__ unsigned short f2bf(float f) {
    uint32_t u = __float_as_uint(f);
    uint32_t r = (u + 0x7fff + ((u >> 16) & 1)) >> 16;
    return (unsigned short)r;
}

// ---------------- prep: cursor = 0 + W1 transpose/convert ----------------

#define ZERO_BLOCKS ((N_NODES + 255) / 256)   // 196
#define PREP_BLOCKS (ZERO_BLOCKS + 256)

__global__ __launch_bounds__(256) void prep_kernel(int* __restrict__ cursor,
                                                   const float* __restrict__ W1,
                                                   unsigned short* __restrict__ Wt) {
    const int t = threadIdx.x;
    if (blockIdx.x < ZERO_BLOCKS) {
        const int i = blockIdx.x * 256 + t;
        if (i < N_NODES) cursor[i] = 0;
    } else {
        const int c = blockIdx.x - ZERO_BLOCKS;   // 0..255
        for (int k = t; k < IN_C; k += 256)
            Wt[c * IN_C + k] = f2bf(W1[k * HID_C + c]);
    }
}

// ---------------- fused GEMM + bucket-fill dispatch ----------------
// FILL blocks first (latency-bound long pole starts at t=0 on all CUs);
// gemm role: tile 128x256, BK=32, A+B double-buffered, counted vmcnt(4) (R15).
// fill role: atomicAdd(cursor[dst]) -> plain ushort store into bucket.

#define FILL_BLOCKS ((N_EDGES + 1023) / 1024)          // 782 (512 thr * 2 edges)
#define GEMM_BLOCKS ((N_NODES + 127) / 128)            // 391
#define GF_BLOCKS (FILL_BLOCKS + GEMM_BLOCKS)
#define NKT 16                                          // 512 / 32

__global__ __launch_bounds__(512) void gf_kernel(
    const float* __restrict__ A,            // [M, 512] f32 (x, read directly)
    const unsigned short* __restrict__ Bt,  // [256, 512] bf16 (W1^T)
    unsigned short* __restrict__ hB,        // [M, 256] bf16 out
    int M,
    const int* __restrict__ src,
    const int* __restrict__ dst,
    int* cursor,
    unsigned short* __restrict__ bucket)
{
    __shared__ float          Asf[2][128 * 32];  // 16 KB each
    __shared__ unsigned short Bs[2][256 * 32];   // 16 KB each
    const int t = threadIdx.x;

    if (blockIdx.x < FILL_BLOCKS) {
        // ---------- fill role: 2 edges/thread ----------
        const int i0 = (blockIdx.x * 512 + t) * 2;
        if (i0 >= N_EDGES) return;
        int s0, d0, s1 = -1, d1 = -1;
        if (i0 + 2 <= N_EDGES) {
            const int2 s2 = *(const int2*)&src[i0];
            const int2 d2 = *(const int2*)&dst[i0];
            s0 = s2.x; s1 = s2.y; d0 = d2.x; d1 = d2.y;
        } else {
            s0 = src[i0]; d0 = dst[i0];
        }
        const int p0 = atomicAdd(&cursor[d0], 1);
        if (p0 < CAP) bucket[d0 * CAP + p0] = (unsigned short)s0;
        if (s1 >= 0) {
            const int p1 = atomicAdd(&cursor[d1], 1);
            if (p1 < CAP) bucket[d1 * CAP + p1] = (unsigned short)s1;
        }
        return;
    }

    // ---------- gemm role (R15 exact) ----------
    const int m0 = (blockIdx.x - FILL_BLOCKS) * 128;
    const int w = t >> 6, l = t & 63;
    const int wr = (w >> 2) * 64;          // 0 / 64
    const int wc = (w & 3) * 64;           // 0 / 64 / 128 / 192
    const int l15 = l & 15, l4 = l >> 4;

    f32x4 acc[4][4] = {};

    auto stage = [&](int buf, int kt) {    // 4 g2l16 per thread (2 A + 2 B)
        #pragma unroll
        for (int q = 0; q < 2; ++q) {       // A: 1024 16B-slots / 512 thr (f32)
            const int idx = q * 512 + t;
            const int row = idx >> 3;
            const int ck  = (idx & 7) ^ (row & 7);
            int gr = m0 + row; if (gr >= M) gr = M - 1;
            g2l16(&A[(size_t)gr * IN_C + kt * 32 + ck * 4], &Asf[buf][idx * 4]);
        }
        #pragma unroll
        for (int q = 0; q < 2; ++q) {       // B: 1024 16B-slots / 512 thr (bf16)
            const int idx = q * 512 + t;
            const int row = idx >> 2;
            const int ck  = (idx & 3) ^ (row & 3) ^ ((row >> 2) & 3);
            g2l16(&Bt[(size_t)row * IN_C + kt * 32 + ck * 8], &Bs[buf][idx * 8]);
        }
    };
    auto compute = [&](int buf) {
        bf16x8 a[4], b[4];
        #pragma unroll
        for (int mi = 0; mi < 4; ++mi) {
            const int r  = wr + mi * 16 + l15;
            const int s0 = l4 * 2;                   // 2 slots of 4 f32 = 8 f32
            const float4 lo = *(const float4*)&Asf[buf][r * 32 + ((s0    ) ^ (r & 7)) * 4];
            const float4 hi = *(const float4*)&Asf[buf][r * 32 + ((s0 + 1) ^ (r & 7)) * 4];
            union { bf16x8 v; __hip_bfloat162 h2[4]; } cv;
            cv.h2[0] = __float22bfloat162_rn(make_float2(lo.x, lo.y));
            cv.h2[1] = __float22bfloat162_rn(make_float2(lo.z, lo.w));
            cv.h2[2] = __float22bfloat162_rn(make_float2(hi.x, hi.y));
            cv.h2[3] = __float22bfloat162_rn(make_float2(hi.z, hi.w));
            a[mi] = cv.v;
        }
        #pragma unroll
        for (int nj = 0; nj < 4; ++nj) {
            const int r  = wc + nj * 16 + l15;
            const int ck = l4 ^ (r & 3) ^ ((r >> 2) & 3);
            b[nj] = *(const bf16x8*)&Bs[buf][r * 32 + ck * 8];
        }
        #pragma unroll
        for (int mi = 0; mi < 4; ++mi)
            #pragma unroll
            for (int nj = 0; nj < 4; ++nj)
                acc[mi][nj] = __builtin_amdgcn_mfma_f32_16x16x32_bf16(
                    a[mi], b[nj], acc[mi][nj], 0, 0, 0);
    };

    stage(0, 0);
    asm volatile("s_waitcnt vmcnt(0)" ::: "memory");
    __builtin_amdgcn_s_barrier();
    int cur = 0;
    for (int kt = 0; kt < NKT; ++kt) {
        if (kt < NKT - 1) {
            stage(cur ^ 1, kt + 1);        // 4 loads issued; fly through compute
            asm volatile("s_waitcnt vmcnt(4)" ::: "memory");   // tile-kt loads landed
        } else {
            asm volatile("s_waitcnt vmcnt(0)" ::: "memory");
        }
        __builtin_amdgcn_s_barrier();      // all waves: LDS tile kt ready
        compute(cur);
        __builtin_amdgcn_s_barrier();      // reads done -> next iter may overwrite
        cur ^= 1;
    }

    #pragma unroll
    for (int mi = 0; mi < 4; ++mi)
        #pragma unroll
        for (int nj = 0; nj < 4; ++nj)
            #pragma unroll
            for (int rr = 0; rr < 4; ++rr) {
                const int m = m0 + wr + mi * 16 + l4 * 4 + rr;
                const int n = wc + nj * 16 + l15;
                if (m < M) hB[(size_t)m * HID_C + n] = f2bf(acc[mi][nj][rr]);
            }
}

// ---------------- agg1: y = dinv[d]*(sum dinv[s]*h[s] + dinv[d]*h[d]); ----------
// ---------------- then relu(y+b1) @ W2 -> h2[d];  dinv = rsqrt(cursor+1) inline.
// 32-lane group per node, 8 feats/lane via uint4, 4-way gather ILP.

__device__ __forceinline__ void fma8(float* acc, uint4 r, float w) {
    acc[0] += __uint_as_float((r.x & 0xffffu) << 16) * w;
    acc[1] += __uint_as_float(r.x & 0xffff0000u) * w;
    acc[2] += __uint_as_float((r.y & 0xffffu) << 16) * w;
    acc[3] += __uint_as_float(r.y & 0xffff0000u) * w;
    acc[4] += __uint_as_float((r.z & 0xffffu) << 16) * w;
    acc[5] += __uint_as_float(r.z & 0xffff0000u) * w;
    acc[6] += __uint_as_float((r.w & 0xffffu) << 16) * w;
    acc[7] += __uint_as_float(r.w & 0xffff0000u) * w;
}

__global__ __launch_bounds__(256) void agg1_kernel(const unsigned short* __restrict__ h, // [N,256] bf16
                                                   const int* __restrict__ cursor,
                                                   const unsigned short* __restrict__ bucket,
                                                   const float* __restrict__ b1,
                                                   const float* __restrict__ W2,  // [256,2]
                                                   float* __restrict__ h2) {      // [N,2]
    const int node = blockIdx.x * 8 + (threadIdx.x >> 5);
    const int g = threadIdx.x & 31;
    const int f0 = g << 3;
    int cnt = cursor[node]; if (cnt > CAP) cnt = CAP;
    const float dv_d = rsqrtf((float)(cursor[node] + 1));

    float acc[8] = {};
    {   // self loop: + dinv[d] * h[d]
        const uint4 rs = *(const uint4*)&h[(size_t)node * HID_C + f0];
        fma8(acc, rs, dv_d);
    }

    const unsigned short* bkt = &bucket[node * CAP];
    for (int base = 0; base < cnt; base += 32) {
        const int rem = cnt - base;
        const int c32 = rem < 32 ? rem : 32;
        int idx = 0; float dv_s = 0.f;
        if (g < c32) {
            idx  = bkt[base + g];
            dv_s = rsqrtf((float)(cursor[idx] + 1));
        }
        int i = 0;
        for (; i + 4 <= c32; i += 4) {
            const int   i0 = __shfl(idx, i,     32); const float w0 = __shfl(dv_s, i,     32);
            const int   i1 = __shfl(idx, i + 1, 32); const float w1 = __shfl(dv_s, i + 1, 32);
            const int   i2 = __shfl(idx, i + 2, 32); const float w2 = __shfl(dv_s, i + 2, 32);
            const int   i3 = __shfl(idx, i + 3, 32); const float w3 = __shfl(dv_s, i + 3, 32);
            const uint4 r0 = *(const uint4*)&h[(size_t)i0 * HID_C + f0];
            const uint4 r1 = *(const uint4*)&h[(size_t)i1 * HID_C + f0];
            const uint4 r2 = *(const uint4*)&h[(size_t)i2 * HID_C + f0];
            const uint4 r3 = *(const uint4*)&h[(size_t)i3 * HID_C + f0];
            fma8(acc, r0, w0); fma8(acc, r1, w1); fma8(acc, r2, w2); fma8(acc, r3, w3);
        }
        for (; i < c32; ++i) {
            const int   ii = __shfl(idx, i, 32);
            const float w  = __shfl(dv_s, i, 32);
            const uint4 r  = *(const uint4*)&h[(size_t)ii * HID_C + f0];
            fma8(acc, r, w);
        }
    }

    const float4 ba = *(const float4*)&b1[f0];
    const float4 bb = *(const float4*)&b1[f0 + 4];
    float v[8];
    v[0] = fmaxf(acc[0] * dv_d + ba.x, 0.f); v[1] = fmaxf(acc[1] * dv_d + ba.y, 0.f);
    v[2] = fmaxf(acc[2] * dv_d + ba.z, 0.f); v[3] = fmaxf(acc[3] * dv_d + ba.w, 0.f);
    v[4] = fmaxf(acc[4] * dv_d + bb.x, 0.f); v[5] = fmaxf(acc[5] * dv_d + bb.y, 0.f);
    v[6] = fmaxf(acc[6] * dv_d + bb.z, 0.f); v[7] = fmaxf(acc[7] * dv_d + bb.w, 0.f);

    float c0 = 0.f, c1 = 0.f;
    #pragma unroll
    for (int q = 0; q < 4; ++q) {
        const float4 wv = *(const float4*)&W2[f0 * 2 + q * 4];  // rows f0+2q, f0+2q+1
        c0 += v[2*q] * wv.x + v[2*q+1] * wv.z;
        c1 += v[2*q] * wv.y + v[2*q+1] * wv.w;
    }
    #pragma unroll
    for (int o = 16; o > 0; o >>= 1) {
        c0 += __shfl_down(c0, o, 32);
        c1 += __shfl_down(c1, o, 32);
    }
    if (g == 0) *(float2*)&h2[node * 2] = make_float2(c0, c1);
}

// ---------------- agg2: out = b2 + dinv[d]*(sum dinv[s]*p[s] + dinv[d]*p[d]) ----

__global__ void agg2_kernel(const float* __restrict__ h2,
                            const int* __restrict__ cursor,
                            const unsigned short* __restrict__ bucket,
                            const float* __restrict__ b2,
                            float* __restrict__ out, int n_nodes) {
    const int n = blockIdx.x * blockDim.x + threadIdx.x;
    if (n >= n_nodes) return;
    int cnt = cursor[n]; if (cnt > CAP) cnt = CAP;
    const float dv_d = rsqrtf((float)(cursor[n] + 1));
    const float2 ps = *(const float2*)&h2[n * 2];
    float a0 = dv_d * ps.x, a1 = dv_d * ps.y;   // self loop
    const unsigned short* bkt = &bucket[n * CAP];
    int i = 0;
    for (; i + 4 <= cnt; i += 4) {
        const uint2 q4 = *(const uint2*)&bkt[i];   // 4 ushort entries (8B aligned)
        const int s0 = q4.x & 0xffff, s1 = q4.x >> 16;
        const int s2 = q4.y & 0xffff, s3 = q4.y >> 16;
        const float w0 = rsqrtf((float)(cursor[s0] + 1));
        const float w1 = rsqrtf((float)(cursor[s1] + 1));
        const float w2 = rsqrtf((float)(cursor[s2] + 1));
        const float w3 = rsqrtf((float)(cursor[s3] + 1));
        const float2 p0 = *(const float2*)&h2[s0 * 2];
        const float2 p1 = *(const float2*)&h2[s1 * 2];
        const float2 p2 = *(const float2*)&h2[s2 * 2];
        const float2 p3 = *(const float2*)&h2[s3 * 2];
        a0 += p0.x * w0 + p1.x * w1 + p2.x * w2 + p3.x * w3;
        a1 += p0.y * w0 + p1.y * w1 + p2.y * w2 + p3.y * w3;
    }
    for (; i < cnt; ++i) {
        const int s = bkt[i];
        const float w = rsqrtf((float)(cursor[s] + 1));
        const float2 p = *(const float2*)&h2[s * 2];
        a0 += p.x * w;
        a1 += p.y * w;
    }
    out[n * 2 + 0] = b2[0] + dv_d * a0;
    out[n * 2 + 1] = b2[1] + dv_d * a1;
}

// ---------------- host ----------------

static inline size_t align_up(size_t x) { return (x + 255) & ~(size_t)255; }

extern "C" void kernel_launch(void* const* d_in, const int* in_sizes, int n_in,
                              void* d_out, int out_size, void* d_ws, size_t ws_size,
                              hipStream_t stream) {
    const float* x   = (const float*)d_in[0];
    const int*   ei  = (const int*)d_in[1];
    const float* W1  = (const float*)d_in[2];
    const float* b1  = (const float*)d_in[3];
    const float* W2  = (const float*)d_in[4];
    const float* b2  = (const float*)d_in[5];
    float* out = (float*)d_out;

    const int* e_src = ei;
    const int* e_dst = ei + N_EDGES;

    char* ws = (char*)d_ws;
    int*   cursor   = (int*)ws;             ws += align_up((size_t)N_NODES * 4);
    unsigned short* bucket = (unsigned short*)ws; ws += align_up((size_t)N_NODES * CAP * 2);
    unsigned short* Wt = (unsigned short*)ws; ws += align_up((size_t)HID_C * IN_C * 2);
    unsigned short* h  = (unsigned short*)ws; ws += align_up((size_t)N_NODES * HID_C * 2);
    float* h2       = (float*)ws;           ws += align_up((size_t)N_NODES * 2 * 4);

    const int nb_n = (N_NODES + 255) / 256;   // 196

    prep_kernel<<<PREP_BLOCKS, 256, 0, stream>>>(cursor, W1, Wt);
    gf_kernel<<<GF_BLOCKS, 512, 0, stream>>>(x, Wt, h, N_NODES,
                                             e_src, e_dst, cursor, bucket);
    agg1_kernel<<<N_NODES / 8, 256, 0, stream>>>(h, cursor, bucket, b1, W2, h2);
    agg2_kernel<<<nb_n, 256, 0, stream>>>(h2, cursor, bucket, b2, out, N_NODES);
}

// Round 22
// 139.237 us; speedup vs baseline: 1.0328x; 1.0328x over previous
//
#include <hip/hip_runtime.h>
#include <hip/hip_bf16.h>
#include <stdint.h>

#define N_NODES 50000
#define N_EDGES 800000
#define IN_C 512
#define HID_C 256
#define CAP 96          // max in-degree capacity (Poisson mean 16, ~12 sigma)

typedef __attribute__((ext_vector_type(8))) short bf16x8;
typedef __attribute__((ext_vector_type(4))) float f32x4;
typedef __attribute__((address_space(3))) uint32_t lds_u32_t;
typedef __attribute__((address_space(1))) const uint32_t g_u32_t;

__device__ __forceinline__ void g2l16(const void* g, void* l) {
    __builtin_amdgcn_global_load_lds((g_u32_t*)g, (lds_u32_t*)l, 16, 0, 0);
}

__device__ __forceinline__ unsigned short f2bf(float f) {
    uint32_t u = __float_as_uint(f);
    uint32_t r = (u + 0x7fff + ((u >> 16) & 1)) >> 16;
    return (unsigned short)r;
}

// ---------------- prep: cursor = 0 + W1 transpose/convert ----------------

#define ZERO_BLOCKS ((N_NODES + 255) / 256)   // 196
#define PREP_BLOCKS (ZERO_BLOCKS + 256)

__global__ __launch_bounds__(256) void prep_kernel(int* __restrict__ cursor,
                                                   const float* __restrict__ W1,
                                                   unsigned short* __restrict__ Wt) {
    const int t = threadIdx.x;
    if (blockIdx.x < ZERO_BLOCKS) {
        const int i = blockIdx.x * 256 + t;
        if (i < N_NODES) cursor[i] = 0;
    } else {
        const int c = blockIdx.x - ZERO_BLOCKS;   // 0..255
        for (int k = t; k < IN_C; k += 256)
            Wt[c * IN_C + k] = f2bf(W1[k * HID_C + c]);
    }
}

// ---------------- fused GEMM + XCD-partitioned bucket-fill ----------------
// gemm role first (R15/R18 proven): tile 128x256, BK=32, dbuf, vmcnt(4).
// fill role: partition p = fb&7 (same-p blocks land on one XCD under
// round-robin dispatch). Block scans an 8192-edge chunk, commits only edges
// with dst&7 == p. Per-XCD dirty bucket set = 1/8 of bucket (~0.6 MB) ->
// L2-resident -> dirty lines evicted once, not once per edge.

#define GEMM_BLOCKS ((N_NODES + 127) / 128)            // 391
#define CHUNKS ((N_EDGES + 8191) / 8192)               // 98
#define FILL_BLOCKS (CHUNKS * 8)                       // 784
#define GF_BLOCKS (GEMM_BLOCKS + FILL_BLOCKS)
#define NKT 16                                          // 512 / 32

__global__ __launch_bounds__(512) void gf_kernel(
    const float* __restrict__ A,            // [M, 512] f32 (x, read directly)
    const unsigned short* __restrict__ Bt,  // [256, 512] bf16 (W1^T)
    unsigned short* __restrict__ hB,        // [M, 256] bf16 out
    int M,
    const int* __restrict__ src,
    const int* __restrict__ dst,
    int* cursor,
    unsigned short* __restrict__ bucket)
{
    __shared__ float          Asf[2][128 * 32];  // 16 KB each
    __shared__ unsigned short Bs[2][256 * 32];   // 16 KB each
    const int t = threadIdx.x;

    if (blockIdx.x >= GEMM_BLOCKS) {
        // ---------- fill role: partitioned scatter ----------
        const int fb = blockIdx.x - GEMM_BLOCKS;
        const int p  = fb & 7;                      // ~XCD id
        const int base = (fb >> 3) * 8192 + t * 16; // 512 thr * 16 edges
        #pragma unroll
        for (int j = 0; j < 4; ++j) {
            const int i = base + j * 4;
            if (i >= N_EDGES) break;                // N_EDGES % 4 == 0
            const int4 d4 = *(const int4*)&dst[i];
            const int4 s4 = *(const int4*)&src[i];
            if ((d4.x & 7) == p) {
                const int q = atomicAdd(&cursor[d4.x], 1);
                if (q < CAP) bucket[d4.x * CAP + q] = (unsigned short)s4.x;
            }
            if ((d4.y & 7) == p) {
                const int q = atomicAdd(&cursor[d4.y], 1);
                if (q < CAP) bucket[d4.y * CAP + q] = (unsigned short)s4.y;
            }
            if ((d4.z & 7) == p) {
                const int q = atomicAdd(&cursor[d4.z], 1);
                if (q < CAP) bucket[d4.z * CAP + q] = (unsigned short)s4.z;
            }
            if ((d4.w & 7) == p) {
                const int q = atomicAdd(&cursor[d4.w], 1);
                if (q < CAP) bucket[d4.w * CAP + q] = (unsigned short)s4.w;
            }
        }
        return;
    }

    // ---------- gemm role (R15 exact) ----------
    const int m0 = blockIdx.x * 128;
    const int w = t >> 6, l = t & 63;
    const int wr = (w >> 2) * 64;          // 0 / 64
    const int wc = (w & 3) * 64;           // 0 / 64 / 128 / 192
    const int l15 = l & 15, l4 = l >> 4;

    f32x4 acc[4][4] = {};

    auto stage = [&](int buf, int kt) {    // 4 g2l16 per thread (2 A + 2 B)
        #pragma unroll
        for (int q = 0; q < 2; ++q) {       // A: 1024 16B-slots / 512 thr (f32)
            const int idx = q * 512 + t;
            const int row = idx >> 3;
            const int ck  = (idx & 7) ^ (row & 7);
            int gr = m0 + row; if (gr >= M) gr = M - 1;
            g2l16(&A[(size_t)gr * IN_C + kt * 32 + ck * 4], &Asf[buf][idx * 4]);
        }
        #pragma unroll
        for (int q = 0; q < 2; ++q) {       // B: 1024 16B-slots / 512 thr (bf16)
            const int idx = q * 512 + t;
            const int row = idx >> 2;
            const int ck  = (idx & 3) ^ (row & 3) ^ ((row >> 2) & 3);
            g2l16(&Bt[(size_t)row * IN_C + kt * 32 + ck * 8], &Bs[buf][idx * 8]);
        }
    };
    auto compute = [&](int buf) {
        bf16x8 a[4], b[4];
        #pragma unroll
        for (int mi = 0; mi < 4; ++mi) {
            const int r  = wr + mi * 16 + l15;
            const int s0 = l4 * 2;                   // 2 slots of 4 f32 = 8 f32
            const float4 lo = *(const float4*)&Asf[buf][r * 32 + ((s0    ) ^ (r & 7)) * 4];
            const float4 hi = *(const float4*)&Asf[buf][r * 32 + ((s0 + 1) ^ (r & 7)) * 4];
            union { bf16x8 v; __hip_bfloat162 h2[4]; } cv;
            cv.h2[0] = __float22bfloat162_rn(make_float2(lo.x, lo.y));
            cv.h2[1] = __float22bfloat162_rn(make_float2(lo.z, lo.w));
            cv.h2[2] = __float22bfloat162_rn(make_float2(hi.x, hi.y));
            cv.h2[3] = __float22bfloat162_rn(make_float2(hi.z, hi.w));
            a[mi] = cv.v;
        }
        #pragma unroll
        for (int nj = 0; nj < 4; ++nj) {
            const int r  = wc + nj * 16 + l15;
            const int ck = l4 ^ (r & 3) ^ ((r >> 2) & 3);
            b[nj] = *(const bf16x8*)&Bs[buf][r * 32 + ck * 8];
        }
        #pragma unroll
        for (int mi = 0; mi < 4; ++mi)
            #pragma unroll
            for (int nj = 0; nj < 4; ++nj)
                acc[mi][nj] = __builtin_amdgcn_mfma_f32_16x16x32_bf16(
                    a[mi], b[nj], acc[mi][nj], 0, 0, 0);
    };

    stage(0, 0);
    asm volatile("s_waitcnt vmcnt(0)" ::: "memory");
    __builtin_amdgcn_s_barrier();
    int cur = 0;
    for (int kt = 0; kt < NKT; ++kt) {
        if (kt < NKT - 1) {
            stage(cur ^ 1, kt + 1);        // 4 loads issued; fly through compute
            asm volatile("s_waitcnt vmcnt(4)" ::: "memory");   // tile-kt loads landed
        } else {
            asm volatile("s_waitcnt vmcnt(0)" ::: "memory");
        }
        __builtin_amdgcn_s_barrier();      // all waves: LDS tile kt ready
        compute(cur);
        __builtin_amdgcn_s_barrier();      // reads done -> next iter may overwrite
        cur ^= 1;
    }

    #pragma unroll
    for (int mi = 0; mi < 4; ++mi)
        #pragma unroll
        for (int nj = 0; nj < 4; ++nj)
            #pragma unroll
            for (int rr = 0; rr < 4; ++rr) {
                const int m = m0 + wr + mi * 16 + l4 * 4 + rr;
                const int n = wc + nj * 16 + l15;
                if (m < M) hB[(size_t)m * HID_C + n] = f2bf(acc[mi][nj][rr]);
            }
}

// ---------------- agg1: dinv inline = rsqrt(cursor+1) ----------------
// 32-lane group per node, 8 feats/lane via uint4, 4-way gather ILP.

__device__ __forceinline__ void fma8(float* acc, uint4 r, float w) {
    acc[0] += __uint_as_float((r.x & 0xffffu) << 16) * w;
    acc[1] += __uint_as_float(r.x & 0xffff0000u) * w;
    acc[2] += __uint_as_float((r.y & 0xffffu) << 16) * w;
    acc[3] += __uint_as_float(r.y & 0xffff0000u) * w;
    acc[4] += __uint_as_float((r.z & 0xffffu) << 16) * w;
    acc[5] += __uint_as_float(r.z & 0xffff0000u) * w;
    acc[6] += __uint_as_float((r.w & 0xffffu) << 16) * w;
    acc[7] += __uint_as_float(r.w & 0xffff0000u) * w;
}

__global__ __launch_bounds__(256) void agg1_kernel(const unsigned short* __restrict__ h, // [N,256] bf16
                                                   const int* __restrict__ cursor,
                                                   const unsigned short* __restrict__ bucket,
                                                   const float* __restrict__ b1,
                                                   const float* __restrict__ W2,  // [256,2]
                                                   float* __restrict__ h2) {      // [N,2]
    const int node = blockIdx.x * 8 + (threadIdx.x >> 5);
    const int g = threadIdx.x & 31;
    const int f0 = g << 3;
    int cnt = cursor[node]; if (cnt > CAP) cnt = CAP;
    const float dv_d = rsqrtf((float)(cursor[node] + 1));

    float acc[8] = {};
    {   // self loop: + dinv[d] * h[d]
        const uint4 rs = *(const uint4*)&h[(size_t)node * HID_C + f0];
        fma8(acc, rs, dv_d);
    }

    const unsigned short* bkt = &bucket[node * CAP];
    for (int base = 0; base < cnt; base += 32) {
        const int rem = cnt - base;
        const int c32 = rem < 32 ? rem : 32;
        int idx = 0; float dv_s = 0.f;
        if (g < c32) {
            idx  = bkt[base + g];
            dv_s = rsqrtf((float)(cursor[idx] + 1));
        }
        int i = 0;
        for (; i + 4 <= c32; i += 4) {
            const int   i0 = __shfl(idx, i,     32); const float w0 = __shfl(dv_s, i,     32);
            const int   i1 = __shfl(idx, i + 1, 32); const float w1 = __shfl(dv_s, i + 1, 32);
            const int   i2 = __shfl(idx, i + 2, 32); const float w2 = __shfl(dv_s, i + 2, 32);
            const int   i3 = __shfl(idx, i + 3, 32); const float w3 = __shfl(dv_s, i + 3, 32);
            const uint4 r0 = *(const uint4*)&h[(size_t)i0 * HID_C + f0];
            const uint4 r1 = *(const uint4*)&h[(size_t)i1 * HID_C + f0];
            const uint4 r2 = *(const uint4*)&h[(size_t)i2 * HID_C + f0];
            const uint4 r3 = *(const uint4*)&h[(size_t)i3 * HID_C + f0];
            fma8(acc, r0, w0); fma8(acc, r1, w1); fma8(acc, r2, w2); fma8(acc, r3, w3);
        }
        for (; i < c32; ++i) {
            const int   ii = __shfl(idx, i, 32);
            const float w  = __shfl(dv_s, i, 32);
            const uint4 r  = *(const uint4*)&h[(size_t)ii * HID_C + f0];
            fma8(acc, r, w);
        }
    }

    const float4 ba = *(const float4*)&b1[f0];
    const float4 bb = *(const float4*)&b1[f0 + 4];
    float v[8];
    v[0] = fmaxf(acc[0] * dv_d + ba.x, 0.f); v[1] = fmaxf(acc[1] * dv_d + ba.y, 0.f);
    v[2] = fmaxf(acc[2] * dv_d + ba.z, 0.f); v[3] = fmaxf(acc[3] * dv_d + ba.w, 0.f);
    v[4] = fmaxf(acc[4] * dv_d + bb.x, 0.f); v[5] = fmaxf(acc[5] * dv_d + bb.y, 0.f);
    v[6] = fmaxf(acc[6] * dv_d + bb.z, 0.f); v[7] = fmaxf(acc[7] * dv_d + bb.w, 0.f);

    float c0 = 0.f, c1 = 0.f;
    #pragma unroll
    for (int q = 0; q < 4; ++q) {
        const float4 wv = *(const float4*)&W2[f0 * 2 + q * 4];  // rows f0+2q, f0+2q+1
        c0 += v[2*q] * wv.x + v[2*q+1] * wv.z;
        c1 += v[2*q] * wv.y + v[2*q+1] * wv.w;
    }
    #pragma unroll
    for (int o = 16; o > 0; o >>= 1) {
        c0 += __shfl_down(c0, o, 32);
        c1 += __shfl_down(c1, o, 32);
    }
    if (g == 0) *(float2*)&h2[node * 2] = make_float2(c0, c1);
}

// ---------------- agg2: out = b2 + dinv[d]*(sum dinv[s]*p[s] + dinv[d]*p[d]) ----

__global__ void agg2_kernel(const float* __restrict__ h2,
                            const int* __restrict__ cursor,
                            const unsigned short* __restrict__ bucket,
                            const float* __restrict__ b2,
                            float* __restrict__ out, int n_nodes) {
    const int n = blockIdx.x * blockDim.x + threadIdx.x;
    if (n >= n_nodes) return;
    int cnt = cursor[n]; if (cnt > CAP) cnt = CAP;
    const float dv_d = rsqrtf((float)(cursor[n] + 1));
    const float2 ps = *(const float2*)&h2[n * 2];
    float a0 = dv_d * ps.x, a1 = dv_d * ps.y;   // self loop
    const unsigned short* bkt = &bucket[n * CAP];
    int i = 0;
    for (; i + 4 <= cnt; i += 4) {
        const uint2 q4 = *(const uint2*)&bkt[i];   // 4 ushort entries (8B aligned)
        const int s0 = q4.x & 0xffff, s1 = q4.x >> 16;
        const int s2 = q4.y & 0xffff, s3 = q4.y >> 16;
        const float w0 = rsqrtf((float)(cursor[s0] + 1));
        const float w1 = rsqrtf((float)(cursor[s1] + 1));
        const float w2 = rsqrtf((float)(cursor[s2] + 1));
        const float w3 = rsqrtf((float)(cursor[s3] + 1));
        const float2 p0 = *(const float2*)&h2[s0 * 2];
        const float2 p1 = *(const float2*)&h2[s1 * 2];
        const float2 p2 = *(const float2*)&h2[s2 * 2];
        const float2 p3 = *(const float2*)&h2[s3 * 2];
        a0 += p0.x * w0 + p1.x * w1 + p2.x * w2 + p3.x * w3;
        a1 += p0.y * w0 + p1.y * w1 + p2.y * w2 + p3.y * w3;
    }
    for (; i < cnt; ++i) {
        const int s = bkt[i];
        const float w = rsqrtf((float)(cursor[s] + 1));
        const float2 p = *(const float2*)&h2[s * 2];
        a0 += p.x * w;
        a1 += p.y * w;
    }
    out[n * 2 + 0] = b2[0] + dv_d * a0;
    out[n * 2 + 1] = b2[1] + dv_d * a1;
}

// ---------------- host ----------------

static inline size_t align_up(size_t x) { return (x + 255) & ~(size_t)255; }

extern "C" void kernel_launch(void* const* d_in, const int* in_sizes, int n_in,
                              void* d_out, int out_size, void* d_ws, size_t ws_size,
                              hipStream_t stream) {
    const float* x   = (const float*)d_in[0];
    const int*   ei  = (const int*)d_in[1];
    const float* W1  = (const float*)d_in[2];
    const float* b1  = (const float*)d_in[3];
    const float* W2  = (const float*)d_in[4];
    const float* b2  = (const float*)d_in[5];
    float* out = (float*)d_out;

    const int* e_src = ei;
    const int* e_dst = ei + N_EDGES;

    char* ws = (char*)d_ws;
    int*   cursor   = (int*)ws;             ws += align_up((size_t)N_NODES * 4);
    unsigned short* bucket = (unsigned short*)ws; ws += align_up((size_t)N_NODES * CAP * 2);
    unsigned short* Wt = (unsigned short*)ws; ws += align_up((size_t)HID_C * IN_C * 2);
    unsigned short* h  = (unsigned short*)ws; ws += align_up((size_t)N_NODES * HID_C * 2);
    float* h2       = (float*)ws;           ws += align_up((size_t)N_NODES * 2 * 4);

    const int nb_n = (N_NODES + 255) / 256;   // 196

    prep_kernel<<<PREP_BLOCKS, 256, 0, stream>>>(cursor, W1, Wt);
    gf_kernel<<<GF_BLOCKS, 512, 0, stream>>>(x, Wt, h, N_NODES,
                                             e_src, e_dst, cursor, bucket);
    agg1_kernel<<<N_NODES / 8, 256, 0, stream>>>(h, cursor, bucket, b1, W2, h2);
    agg2_kernel<<<nb_n, 256, 0, stream>>>(h2, cursor, bucket, b2, out, N_NODES);
}

// Round 23
// 128.100 us; speedup vs baseline: 1.1226x; 1.0869x over previous
//
#include <hip/hip_runtime.h>
#include <hip/hip_bf16.h>
#include <stdint.h>

#define N_NODES 50000
#define N_EDGES 800000
#define IN_C 512
#define HID_C 256
#define CAP 96          // max in-degree capacity (Poisson mean 16, ~12 sigma)

typedef __attribute__((ext_vector_type(8))) short bf16x8;
typedef __attribute__((ext_vector_type(4))) float f32x4;
typedef __attribute__((address_space(3))) uint32_t lds_u32_t;
typedef __attribute__((address_space(1))) const uint32_t g_u32_t;

__device__ __forceinline__ void g2l16(const void* g, void* l) {
    __builtin_amdgcn_global_load_lds((g_u32_t*)g, (lds_u32_t*)l, 16, 0, 0);
}

__device__ __forceinline__ unsigned short f2bf(float f) {
    uint32_t u = __float_as_uint(f);
    uint32_t r = (u + 0x7fff + ((u >> 16) & 1)) >> 16;
    return (unsigned short)r;
}

// ---------------- prep: cursor = 0 + LDS-tiled W1 transpose/convert ----------------
// transpose role: 32 blocks, 64x64 f32 tiles; coalesced load W1 rows,
// coalesced store Wt rows, LDS [64][66] ushort (conflict-free).

#define ZERO_BLOCKS ((N_NODES + 255) / 256)   // 196
#define TW_BLOCKS 32                           // (512/64) * (256/64)
#define PREP_BLOCKS (ZERO_BLOCKS + TW_BLOCKS)

__global__ __launch_bounds__(256) void prep_kernel(int* __restrict__ cursor,
                                                   const float* __restrict__ W1,
                                                   unsigned short* __restrict__ Wt) {
    const int t = threadIdx.x;
    if (blockIdx.x < ZERO_BLOCKS) {
        const int i = blockIdx.x * 256 + t;
        if (i < N_NODES) cursor[i] = 0;
        return;
    }
    __shared__ unsigned short tile[64][66];
    const int b  = blockIdx.x - ZERO_BLOCKS;   // 0..31
    const int k0 = (b >> 2) * 64;              // 0..448
    const int c0 = (b & 3) * 64;               // 0..192
    const int tr = t >> 6, tc = t & 63;
    #pragma unroll
    for (int rr = 0; rr < 16; ++rr) {
        const int row = rr * 4 + tr;           // k offset
        tile[row][tc] = f2bf(W1[(size_t)(k0 + row) * HID_C + c0 + tc]);
    }
    __syncthreads();
    #pragma unroll
    for (int rr = 0; rr < 16; ++rr) {
        const int row = rr * 4 + tr;           // c offset
        Wt[(size_t)(c0 + row) * IN_C + k0 + tc] = tile[tc][row];
    }
}

// ---------------- fused GEMM + bucket-fill dispatch (R18 exact) ----------------
// gemm role: tile 128x256, BK=32, A+B double-buffered, counted vmcnt(4).
// fill role: atomicAdd(cursor) -> plain ushort store into bucket.

#define GEMM_BLOCKS ((N_NODES + 127) / 128)            // 391
#define FILL_BLOCKS ((N_EDGES + 1023) / 1024)          // 782 (512 thr * 2 edges)
#define GF_BLOCKS (GEMM_BLOCKS + FILL_BLOCKS)
#define NKT 16                                          // 512 / 32

__global__ __launch_bounds__(512) void gf_kernel(
    const float* __restrict__ A,            // [M, 512] f32 (x, read directly)
    const unsigned short* __restrict__ Bt,  // [256, 512] bf16 (W1^T)
    unsigned short* __restrict__ hB,        // [M, 256] bf16 out
    int M,
    const int* __restrict__ src,
    const int* __restrict__ dst,
    int* cursor,
    unsigned short* __restrict__ bucket)
{
    __shared__ float          Asf[2][128 * 32];  // 16 KB each
    __shared__ unsigned short Bs[2][256 * 32];   // 16 KB each
    const int t = threadIdx.x;

    if (blockIdx.x >= GEMM_BLOCKS) {
        // ---------- fill role: 2 edges/thread ----------
        const int i0 = ((blockIdx.x - GEMM_BLOCKS) * 512 + t) * 2;
        if (i0 >= N_EDGES) return;
        int s0, d0, s1 = -1, d1 = -1;
        if (i0 + 2 <= N_EDGES) {
            const int2 s2 = *(const int2*)&src[i0];
            const int2 d2 = *(const int2*)&dst[i0];
            s0 = s2.x; s1 = s2.y; d0 = d2.x; d1 = d2.y;
        } else {
            s0 = src[i0]; d0 = dst[i0];
        }
        const int p0 = atomicAdd(&cursor[d0], 1);
        if (p0 < CAP) bucket[d0 * CAP + p0] = (unsigned short)s0;
        if (s1 >= 0) {
            const int p1 = atomicAdd(&cursor[d1], 1);
            if (p1 < CAP) bucket[d1 * CAP + p1] = (unsigned short)s1;
        }
        return;
    }

    // ---------- gemm role ----------
    const int m0 = blockIdx.x * 128;
    const int w = t >> 6, l = t & 63;
    const int wr = (w >> 2) * 64;          // 0 / 64
    const int wc = (w & 3) * 64;           // 0 / 64 / 128 / 192
    const int l15 = l & 15, l4 = l >> 4;

    f32x4 acc[4][4] = {};

    auto stage = [&](int buf, int kt) {    // 4 g2l16 per thread (2 A + 2 B)
        #pragma unroll
        for (int q = 0; q < 2; ++q) {       // A: 1024 16B-slots / 512 thr (f32)
            const int idx = q * 512 + t;
            const int row = idx >> 3;
            const int ck  = (idx & 7) ^ (row & 7);
            int gr = m0 + row; if (gr >= M) gr = M - 1;
            g2l16(&A[(size_t)gr * IN_C + kt * 32 + ck * 4], &Asf[buf][idx * 4]);
        }
        #pragma unroll
        for (int q = 0; q < 2; ++q) {       // B: 1024 16B-slots / 512 thr (bf16)
            const int idx = q * 512 + t;
            const int row = idx >> 2;
            const int ck  = (idx & 3) ^ (row & 3) ^ ((row >> 2) & 3);
            g2l16(&Bt[(size_t)row * IN_C + kt * 32 + ck * 8], &Bs[buf][idx * 8]);
        }
    };
    auto compute = [&](int buf) {
        bf16x8 a[4], b[4];
        #pragma unroll
        for (int mi = 0; mi < 4; ++mi) {
            const int r  = wr + mi * 16 + l15;
            const int s0 = l4 * 2;                   // 2 slots of 4 f32 = 8 f32
            const float4 lo = *(const float4*)&Asf[buf][r * 32 + ((s0    ) ^ (r & 7)) * 4];
            const float4 hi = *(const float4*)&Asf[buf][r * 32 + ((s0 + 1) ^ (r & 7)) * 4];
            union { bf16x8 v; __hip_bfloat162 h2[4]; } cv;
            cv.h2[0] = __float22bfloat162_rn(make_float2(lo.x, lo.y));
            cv.h2[1] = __float22bfloat162_rn(make_float2(lo.z, lo.w));
            cv.h2[2] = __float22bfloat162_rn(make_float2(hi.x, hi.y));
            cv.h2[3] = __float22bfloat162_rn(make_float2(hi.z, hi.w));
            a[mi] = cv.v;
        }
        #pragma unroll
        for (int nj = 0; nj < 4; ++nj) {
            const int r  = wc + nj * 16 + l15;
            const int ck = l4 ^ (r & 3) ^ ((r >> 2) & 3);
            b[nj] = *(const bf16x8*)&Bs[buf][r * 32 + ck * 8];
        }
        #pragma unroll
        for (int mi = 0; mi < 4; ++mi)
            #pragma unroll
            for (int nj = 0; nj < 4; ++nj)
                acc[mi][nj] = __builtin_amdgcn_mfma_f32_16x16x32_bf16(
                    a[mi], b[nj], acc[mi][nj], 0, 0, 0);
    };

    stage(0, 0);
    asm volatile("s_waitcnt vmcnt(0)" ::: "memory");
    __builtin_amdgcn_s_barrier();
    int cur = 0;
    for (int kt = 0; kt < NKT; ++kt) {
        if (kt < NKT - 1) {
            stage(cur ^ 1, kt + 1);        // 4 loads issued; fly through compute
            asm volatile("s_waitcnt vmcnt(4)" ::: "memory");   // tile-kt loads landed
        } else {
            asm volatile("s_waitcnt vmcnt(0)" ::: "memory");
        }
        __builtin_amdgcn_s_barrier();      // all waves: LDS tile kt ready
        compute(cur);
        __builtin_amdgcn_s_barrier();      // reads done -> next iter may overwrite
        cur ^= 1;
    }

    #pragma unroll
    for (int mi = 0; mi < 4; ++mi)
        #pragma unroll
        for (int nj = 0; nj < 4; ++nj)
            #pragma unroll
            for (int rr = 0; rr < 4; ++rr) {
                const int m = m0 + wr + mi * 16 + l4 * 4 + rr;
                const int n = wc + nj * 16 + l15;
                if (m < M) hB[(size_t)m * HID_C + n] = f2bf(acc[mi][nj][rr]);
            }
}

// ---------------- agg1: dinv inline = rsqrt(cursor+1) ----------------
// 32-lane group per node, 8 feats/lane via uint4, 4-way gather ILP.

__device__ __forceinline__ void fma8(float* acc, uint4 r, float w) {
    acc[0] += __uint_as_float((r.x & 0xffffu) << 16) * w;
    acc[1] += __uint_as_float(r.x & 0xffff0000u) * w;
    acc[2] += __uint_as_float((r.y & 0xffffu) << 16) * w;
    acc[3] += __uint_as_float(r.y & 0xffff0000u) * w;
    acc[4] += __uint_as_float((r.z & 0xffffu) << 16) * w;
    acc[5] += __uint_as_float(r.z & 0xffff0000u) * w;
    acc[6] += __uint_as_float((r.w & 0xffffu) << 16) * w;
    acc[7] += __uint_as_float(r.w & 0xffff0000u) * w;
}

__global__ __launch_bounds__(256) void agg1_kernel(const unsigned short* __restrict__ h, // [N,256] bf16
                                                   const int* __restrict__ cursor,
                                                   const unsigned short* __restrict__ bucket,
                                                   const float* __restrict__ b1,
                                                   const float* __restrict__ W2,  // [256,2]
                                                   float* __restrict__ h2) {      // [N,2]
    const int node = blockIdx.x * 8 + (threadIdx.x >> 5);
    const int g = threadIdx.x & 31;
    const int f0 = g << 3;
    int cnt = cursor[node]; if (cnt > CAP) cnt = CAP;
    const float dv_d = rsqrtf((float)(cursor[node] + 1));

    float acc[8] = {};
    {   // self loop: + dinv[d] * h[d]
        const uint4 rs = *(const uint4*)&h[(size_t)node * HID_C + f0];
        fma8(acc, rs, dv_d);
    }

    const unsigned short* bkt = &bucket[node * CAP];
    for (int base = 0; base < cnt; base += 32) {
        const int rem = cnt - base;
        const int c32 = rem < 32 ? rem : 32;
        int idx = 0; float dv_s = 0.f;
        if (g < c32) {
            idx  = bkt[base + g];
            dv_s = rsqrtf((float)(cursor[idx] + 1));
        }
        int i = 0;
        for (; i + 4 <= c32; i += 4) {
            const int   i0 = __shfl(idx, i,     32); const float w0 = __shfl(dv_s, i,     32);
            const int   i1 = __shfl(idx, i + 1, 32); const float w1 = __shfl(dv_s, i + 1, 32);
            const int   i2 = __shfl(idx, i + 2, 32); const float w2 = __shfl(dv_s, i + 2, 32);
            const int   i3 = __shfl(idx, i + 3, 32); const float w3 = __shfl(dv_s, i + 3, 32);
            const uint4 r0 = *(const uint4*)&h[(size_t)i0 * HID_C + f0];
            const uint4 r1 = *(const uint4*)&h[(size_t)i1 * HID_C + f0];
            const uint4 r2 = *(const uint4*)&h[(size_t)i2 * HID_C + f0];
            const uint4 r3 = *(const uint4*)&h[(size_t)i3 * HID_C + f0];
            fma8(acc, r0, w0); fma8(acc, r1, w1); fma8(acc, r2, w2); fma8(acc, r3, w3);
        }
        for (; i < c32; ++i) {
            const int   ii = __shfl(idx, i, 32);
            const float w  = __shfl(dv_s, i, 32);
            const uint4 r  = *(const uint4*)&h[(size_t)ii * HID_C + f0];
            fma8(acc, r, w);
        }
    }

    const float4 ba = *(const float4*)&b1[f0];
    const float4 bb = *(const float4*)&b1[f0 + 4];
    float v[8];
    v[0] = fmaxf(acc[0] * dv_d + ba.x, 0.f); v[1] = fmaxf(acc[1] * dv_d + ba.y, 0.f);
    v[2] = fmaxf(acc[2] * dv_d + ba.z, 0.f); v[3] = fmaxf(acc[3] * dv_d + ba.w, 0.f);
    v[4] = fmaxf(acc[4] * dv_d + bb.x, 0.f); v[5] = fmaxf(acc[5] * dv_d + bb.y, 0.f);
    v[6] = fmaxf(acc[6] * dv_d + bb.z, 0.f); v[7] = fmaxf(acc[7] * dv_d + bb.w, 0.f);

    float c0 = 0.f, c1 = 0.f;
    #pragma unroll
    for (int q = 0; q < 4; ++q) {
        const float4 wv = *(const float4*)&W2[f0 * 2 + q * 4];  // rows f0+2q, f0+2q+1
        c0 += v[2*q] * wv.x + v[2*q+1] * wv.z;
        c1 += v[2*q] * wv.y + v[2*q+1] * wv.w;
    }
    #pragma unroll
    for (int o = 16; o > 0; o >>= 1) {
        c0 += __shfl_down(c0, o, 32);
        c1 += __shfl_down(c1, o, 32);
    }
    if (g == 0) *(float2*)&h2[node * 2] = make_float2(c0, c1);
}

// ---------------- agg2: out = b2 + dinv[d]*(sum dinv[s]*p[s] + dinv[d]*p[d]) ----

__global__ void agg2_kernel(const float* __restrict__ h2,
                            const int* __restrict__ cursor,
                            const unsigned short* __restrict__ bucket,
                            const float* __restrict__ b2,
                            float* __restrict__ out, int n_nodes) {
    const int n = blockIdx.x * blockDim.x + threadIdx.x;
    if (n >= n_nodes) return;
    int cnt = cursor[n]; if (cnt > CAP) cnt = CAP;
    const float dv_d = rsqrtf((float)(cursor[n] + 1));
    const float2 ps = *(const float2*)&h2[n * 2];
    float a0 = dv_d * ps.x, a1 = dv_d * ps.y;   // self loop
    const unsigned short* bkt = &bucket[n * CAP];
    int i = 0;
    for (; i + 4 <= cnt; i += 4) {
        const uint2 q4 = *(const uint2*)&bkt[i];   // 4 ushort entries (8B aligned)
        const int s0 = q4.x & 0xffff, s1 = q4.x >> 16;
        const int s2 = q4.y & 0xffff, s3 = q4.y >> 16;
        const float w0 = rsqrtf((float)(cursor[s0] + 1));
        const float w1 = rsqrtf((float)(cursor[s1] + 1));
        const float w2 = rsqrtf((float)(cursor[s2] + 1));
        const float w3 = rsqrtf((float)(cursor[s3] + 1));
        const float2 p0 = *(const float2*)&h2[s0 * 2];
        const float2 p1 = *(const float2*)&h2[s1 * 2];
        const float2 p2 = *(const float2*)&h2[s2 * 2];
        const float2 p3 = *(const float2*)&h2[s3 * 2];
        a0 += p0.x * w0 + p1.x * w1 + p2.x * w2 + p3.x * w3;
        a1 += p0.y * w0 + p1.y * w1 + p2.y * w2 + p3.y * w3;
    }
    for (; i < cnt; ++i) {
        const int s = bkt[i];
        const float w = rsqrtf((float)(cursor[s] + 1));
        const float2 p = *(const float2*)&h2[s * 2];
        a0 += p.x * w;
        a1 += p.y * w;
    }
    out[n * 2 + 0] = b2[0] + dv_d * a0;
    out[n * 2 + 1] = b2[1] + dv_d * a1;
}

// ---------------- host ----------------

static inline size_t align_up(size_t x) { return (x + 255) & ~(size_t)255; }

extern "C" void kernel_launch(void* const* d_in, const int* in_sizes, int n_in,
                              void* d_out, int out_size, void* d_ws, size_t ws_size,
                              hipStream_t stream) {
    const float* x   = (const float*)d_in[0];
    const int*   ei  = (const int*)d_in[1];
    const float* W1  = (const float*)d_in[2];
    const float* b1  = (const float*)d_in[3];
    const float* W2  = (const float*)d_in[4];
    const float* b2  = (const float*)d_in[5];
    float* out = (float*)d_out;

    const int* e_src = ei;
    const int* e_dst = ei + N_EDGES;

    char* ws = (char*)d_ws;
    int*   cursor   = (int*)ws;             ws += align_up((size_t)N_NODES * 4);
    unsigned short* bucket = (unsigned short*)ws; ws += align_up((size_t)N_NODES * CAP * 2);
    unsigned short* Wt = (unsigned short*)ws; ws += align_up((size_t)HID_C * IN_C * 2);
    unsigned short* h  = (unsigned short*)ws; ws += align_up((size_t)N_NODES * HID_C * 2);
    float* h2       = (float*)ws;           ws += align_up((size_t)N_NODES * 2 * 4);

    const int nb_n = (N_NODES + 255) / 256;   // 196

    prep_kernel<<<PREP_BLOCKS, 256, 0, stream>>>(cursor, W1, Wt);
    gf_kernel<<<GF_BLOCKS, 512, 0, stream>>>(x, Wt, h, N_NODES,
                                             e_src, e_dst, cursor, bucket);
    agg1_kernel<<<N_NODES / 8, 256, 0, stream>>>(h, cursor, bucket, b1, W2, h2);
    agg2_kernel<<<nb_n, 256, 0, stream>>>(h2, cursor, bucket, b2, out, N_NODES);
}